// Round 9
// baseline (90.519 us; speedup 1.0000x reference)
//
#include <hip/hip_runtime.h>

#define CH 128          // IN_CH == OUT_CH == 128
#define GM 64           // rows per GEMM block == BNODES (gemm block b == bucket b)
#define LDK 136         // padded K stride in LDS
#define BSH 6           // log2(nodes per bucket)
#define BNODES 64       // nodes per bucket
#define CAP 3072        // per-bucket pair capacity (lambda=1024; spill handles excess)
#define MAXB 1024       // LDS cap for bucket arrays (NB=782 for N=50000)

typedef _Float16 f16x4 __attribute__((ext_vector_type(4)));
typedef float    f32x4 __attribute__((ext_vector_type(4)));
typedef unsigned short u16x8 __attribute__((ext_vector_type(8)));

static __host__ __device__ inline size_t align256(size_t x) { return (x + 255) & ~(size_t)255; }

__device__ inline unsigned short f2b(float f) {   // fp32 -> bf16 RNE
    unsigned int u = __float_as_uint(f);
    return (unsigned short)((u + 0x7fffu + ((u >> 16) & 1u)) >> 16);
}
__device__ inline float b2f(unsigned short h) {
    return __uint_as_float(((unsigned int)h) << 16);
}

// ---------------- bin edges into fixed-capacity buckets + W f16-transpose --------
// pairs[b*CAP + slot] = (src<<6)|(dst&63).  Overflow -> spill list (normally empty).

__global__ __launch_bounds__(256) void k_bin(const int* __restrict__ ei,
                                             int* __restrict__ gcur,      // [nb+1]; [nb]=spill cnt
                                             unsigned int* __restrict__ pairs,
                                             unsigned int* __restrict__ spill,
                                             int e, int nb,
                                             const float* __restrict__ W,
                                             unsigned short* __restrict__ WT) {
    __shared__ int lcnt[MAXB], lbase[MAXB], lpos[MAXB];
    const int t = threadIdx.x;

    // fused W prep: fp32 [k][n] -> f16 bits transposed [n][k]; first 8 blocks
    if (blockIdx.x < 8) {
        int wb = blockIdx.x * 2048;
#pragma unroll
        for (int i = 0; i < 8; ++i) {
            int idx = wb + t + i * 256;
            int k = idx >> 7, nn = idx & 127;
            _Float16 h = (_Float16)W[idx];
            WT[nn * CH + k] = *(unsigned short*)&h;
        }
    }

    for (int i = t; i < nb; i += 256) { lcnt[i] = 0; lpos[i] = 0; }
    __syncthreads();

    // stage 16 edges/thread via int4
    const int base = blockIdx.x * 4096;
    const int e4 = e >> 2;                       // e % 4 == 0 for this problem
    int4 s4[4], d4[4];
#pragma unroll
    for (int r = 0; r < 4; ++r) {
        int q = (base >> 2) + t + r * 256;
        if (q < e4) {
            s4[r] = ((const int4*)ei)[q];
            d4[r] = ((const int4*)(ei + e))[q];
        } else {
            s4[r] = make_int4(-1, -1, -1, -1);
            d4[r] = make_int4(0, 0, 0, 0);
        }
    }
    const int* ss = (const int*)s4;
    const int* dd = (const int*)d4;
#pragma unroll
    for (int i = 0; i < 16; ++i)
        if (ss[i] >= 0) atomicAdd(&lcnt[dd[i] >> BSH], 1);
    __syncthreads();
    for (int i = t; i < nb; i += 256)
        if (lcnt[i]) lbase[i] = atomicAdd(&gcur[i], lcnt[i]);
    __syncthreads();
#pragma unroll
    for (int i = 0; i < 16; ++i) {
        if (ss[i] >= 0) {
            int b = dd[i] >> BSH;
            int p = lbase[b] + atomicAdd(&lpos[b], 1);
            if (p < CAP) {
                pairs[(size_t)b * CAP + p] = ((unsigned)ss[i] << BSH) | (unsigned)(dd[i] & (BNODES - 1));
            } else {
                int sp = atomicAdd(&gcur[nb], 1);
                spill[sp] = ((unsigned)ss[i] << 16) | (unsigned)dd[i];
            }
        }
    }
}

// ---------------- GEMM + fused per-bucket degree/dinv ---------------------------

__global__ __launch_bounds__(256) void k_gemm(const float* __restrict__ x,
                                              const unsigned short* __restrict__ WT,
                                              const unsigned int* __restrict__ pairs,
                                              const int* __restrict__ gcur,
                                              const unsigned int* __restrict__ spill,
                                              float* __restrict__ dinv,
                                              unsigned short* __restrict__ hs_b,
                                              int n, int nb) {
    __shared__ unsigned short sA[GM * LDK];
    __shared__ unsigned short sB[CH * LDK];
    __shared__ int   scnt[GM];
    __shared__ float sdv[GM];

    const int tid = threadIdx.x;
    const int b   = blockIdx.x;
    const int r0  = b * GM;

    if (tid < GM) scnt[tid] = 0;

    const u16x8* Wv = (const u16x8*)WT;
#pragma unroll
    for (int i = 0; i < 8; ++i) {
        int c = tid + i * 256;
        int nr = c >> 4, kq = c & 15;
        *(u16x8*)&sB[nr * LDK + kq * 8] = Wv[c];
    }
#pragma unroll
    for (int i = 0; i < 8; ++i) {
        int c = tid + i * 256;
        int r = c >> 5, cq = c & 31;
        f32x4 v = (f32x4){0.f, 0.f, 0.f, 0.f};
        if (r0 + r < n) v = __builtin_nontemporal_load(&((const f32x4*)x)[(size_t)(r0 + r) * 32 + cq]);
        f16x4 h;
        h[0] = (_Float16)v[0]; h[1] = (_Float16)v[1];
        h[2] = (_Float16)v[2]; h[3] = (_Float16)v[3];
        *(f16x4*)&sA[r * LDK + cq * 4] = h;
    }
    __syncthreads();

    // fused degree histogram (overlaps with MFMA issue below)
    {
        const int cntb = min(gcur[b], CAP);
        const unsigned int* pp = pairs + (size_t)b * CAP;
        for (int j = tid; j < cntb; j += 256)
            atomicAdd(&scnt[pp[j] & (BNODES - 1)], 1);
        const int ns = gcur[nb];
        if (ns > 0) {
            for (int j = tid; j < ns; j += 256) {
                unsigned u = spill[j];
                unsigned du = u & 0xffffu;
                if ((int)(du >> BSH) == b) atomicAdd(&scnt[du & (BNODES - 1)], 1);
            }
        }
    }

    const int lane = tid & 63, w = tid >> 6;
    const int mh = (w >> 1) * 32;
    const int nh = (w & 1) * 64;
    const int fr = lane & 15, fg = lane >> 4;

    f32x4 acc[2][4];
#pragma unroll
    for (int a = 0; a < 2; ++a)
#pragma unroll
        for (int bq = 0; bq < 4; ++bq) acc[a][bq] = (f32x4){0.f, 0.f, 0.f, 0.f};

#pragma unroll
    for (int ks = 0; ks < 8; ++ks) {
        const int kk = ks * 16 + fg * 4;
        f16x4 a0 = *(const f16x4*)&sA[(mh + fr) * LDK + kk];
        f16x4 a1 = *(const f16x4*)&sA[(mh + 16 + fr) * LDK + kk];
        f16x4 b0 = *(const f16x4*)&sB[(nh + fr) * LDK + kk];
        f16x4 b1 = *(const f16x4*)&sB[(nh + 16 + fr) * LDK + kk];
        f16x4 b2 = *(const f16x4*)&sB[(nh + 32 + fr) * LDK + kk];
        f16x4 b3 = *(const f16x4*)&sB[(nh + 48 + fr) * LDK + kk];
        acc[0][0] = __builtin_amdgcn_mfma_f32_16x16x16f16(a0, b0, acc[0][0], 0, 0, 0);
        acc[0][1] = __builtin_amdgcn_mfma_f32_16x16x16f16(a0, b1, acc[0][1], 0, 0, 0);
        acc[0][2] = __builtin_amdgcn_mfma_f32_16x16x16f16(a0, b2, acc[0][2], 0, 0, 0);
        acc[0][3] = __builtin_amdgcn_mfma_f32_16x16x16f16(a0, b3, acc[0][3], 0, 0, 0);
        acc[1][0] = __builtin_amdgcn_mfma_f32_16x16x16f16(a1, b0, acc[1][0], 0, 0, 0);
        acc[1][1] = __builtin_amdgcn_mfma_f32_16x16x16f16(a1, b1, acc[1][1], 0, 0, 0);
        acc[1][2] = __builtin_amdgcn_mfma_f32_16x16x16f16(a1, b2, acc[1][2], 0, 0, 0);
        acc[1][3] = __builtin_amdgcn_mfma_f32_16x16x16f16(a1, b3, acc[1][3], 0, 0, 0);
    }
    __syncthreads();                 // histogram atomics complete

    if (tid < GM) {
        float dv = rsqrtf((float)scnt[tid] + 1.0f);
        sdv[tid] = dv;
        int node = r0 + tid;
        if (node < n) dinv[node] = dv;
    }
    __syncthreads();                 // sdv visible to all

#pragma unroll
    for (int mt = 0; mt < 2; ++mt) {
        int lbase_r = mh + mt * 16 + fg * 4;
        int rbase = r0 + lbase_r;
#pragma unroll
        for (int nt = 0; nt < 4; ++nt) {
            int col = nh + nt * 16 + fr;
#pragma unroll
            for (int rg = 0; rg < 4; ++rg) {
                if (rbase + rg < n)
                    hs_b[(size_t)(rbase + rg) * CH + col] = f2b(acc[mt][nt][rg] * sdv[lbase_r + rg]);
            }
        }
    }
}

// ---------------- fused sort+gather per bucket --------------------------------
// 512 threads for more outstanding misses; nontemporal row loads bypass L1
// allocation (rows touched exactly once).

__global__ __launch_bounds__(512) void k_gagg(const u16x8* __restrict__ h8,
                                              const unsigned int* __restrict__ pairs,
                                              const int* __restrict__ gcur,
                                              const unsigned int* __restrict__ spill,
                                              const float* __restrict__ dinv,
                                              const float* __restrict__ bias,
                                              float* __restrict__ out, int n, int nb) {
    __shared__ unsigned int   sPairs[CAP];
    __shared__ unsigned short sSort[CAP];
    __shared__ int scnt[BNODES], sexcl[BNODES], scur[BNODES];
    __shared__ float sdinv[BNODES];

    const int t = threadIdx.x, b = blockIdx.x;
    const int n0 = b * BNODES;

    if (t < BNODES) {
        scnt[t] = 0;
        int node = n0 + t;
        sdinv[t] = (node < n) ? dinv[node] : 0.f;
    }
    __syncthreads();

    const int cntb = min(gcur[b], CAP);
    const unsigned int* pp = pairs + (size_t)b * CAP;
    for (int j = t; j < cntb; j += 512) {
        unsigned p = pp[j];
        sPairs[j] = p;
        atomicAdd(&scnt[p & (BNODES - 1)], 1);
    }
    __syncthreads();

    if (t < 64) {          // BNODES == 64: one wave scans the counts
        int c = scnt[t];
        int s = c;
#pragma unroll
        for (int off = 1; off < 64; off <<= 1) {
            int tv = __shfl_up(s, off, 64);
            if (t >= off) s += tv;
        }
        sexcl[t] = s - c;
        scur[t]  = s - c;
    }
    __syncthreads();

    for (int j = t; j < cntb; j += 512) {
        unsigned p = sPairs[j];
        int pos = atomicAdd(&scur[p & (BNODES - 1)], 1);
        sSort[pos] = (unsigned short)(p >> BSH);
    }
    __syncthreads();

    const int g = t >> 4, lane = t & 15;        // 32 groups of 16 lanes
    const int ns = gcur[nb];
#pragma unroll
    for (int k = 0; k < 2; ++k) {               // 2 nodes per group
        const int nl = g * 2 + k;
        const int node = n0 + nl;
        if (node >= n) break;

        float acc[8];
        {
            u16x8 v = __builtin_nontemporal_load(&h8[(size_t)node * 16 + lane]);  // self term
#pragma unroll
            for (int i = 0; i < 8; ++i) acc[i] = b2f(v[i]);
        }

        int j = sexcl[nl];
        const int end = j + scnt[nl];
        for (; j + 4 <= end; j += 4) {
            int s0 = sSort[j + 0], s1 = sSort[j + 1];
            int s2 = sSort[j + 2], s3 = sSort[j + 3];
            u16x8 v0 = __builtin_nontemporal_load(&h8[(size_t)s0 * 16 + lane]);
            u16x8 v1 = __builtin_nontemporal_load(&h8[(size_t)s1 * 16 + lane]);
            u16x8 v2 = __builtin_nontemporal_load(&h8[(size_t)s2 * 16 + lane]);
            u16x8 v3 = __builtin_nontemporal_load(&h8[(size_t)s3 * 16 + lane]);
#pragma unroll
            for (int i = 0; i < 8; ++i)
                acc[i] += (b2f(v0[i]) + b2f(v1[i])) + (b2f(v2[i]) + b2f(v3[i]));
        }
        for (; j < end; ++j) {
            u16x8 v = __builtin_nontemporal_load(&h8[(size_t)sSort[j] * 16 + lane]);
#pragma unroll
            for (int i = 0; i < 8; ++i) acc[i] += b2f(v[i]);
        }

        if (ns > 0) {      // cold path: spilled edges for this node
            for (int q = 0; q < ns; ++q) {
                unsigned u = spill[q];
                if ((int)(u & 0xffffu) == node) {
                    u16x8 v = h8[(size_t)(u >> 16) * 16 + lane];
#pragma unroll
                    for (int i = 0; i < 8; ++i) acc[i] += b2f(v[i]);
                }
            }
        }

        const float di = sdinv[nl];
        const float* bp = bias + lane * 8;
        f32x4 o0, o1;
        o0[0] = fmaxf(fmaf(acc[0], di, bp[0]), 0.f);
        o0[1] = fmaxf(fmaf(acc[1], di, bp[1]), 0.f);
        o0[2] = fmaxf(fmaf(acc[2], di, bp[2]), 0.f);
        o0[3] = fmaxf(fmaf(acc[3], di, bp[3]), 0.f);
        o1[0] = fmaxf(fmaf(acc[4], di, bp[4]), 0.f);
        o1[1] = fmaxf(fmaf(acc[5], di, bp[5]), 0.f);
        o1[2] = fmaxf(fmaf(acc[6], di, bp[6]), 0.f);
        o1[3] = fmaxf(fmaf(acc[7], di, bp[7]), 0.f);
        f32x4* op = (f32x4*)(out + (size_t)node * CH + lane * 8);
        __builtin_nontemporal_store(o0, &op[0]);
        __builtin_nontemporal_store(o1, &op[1]);
    }
}

// ---------------- launch ----------------

extern "C" void kernel_launch(void* const* d_in, const int* in_sizes, int n_in,
                              void* d_out, int out_size, void* d_ws, size_t ws_size,
                              hipStream_t stream) {
    const float* x  = (const float*)d_in[0];
    const int*   ei = (const int*)d_in[1];
    const float* W  = (const float*)d_in[2];
    const float* b  = (const float*)d_in[3];
    float* out = (float*)d_out;

    const int N = in_sizes[0] / CH;     // 50000 (node ids < 65536 -> 16-bit packing valid)
    const int E = in_sizes[1] / 2;      // 800000

    const int NB = (N + BNODES - 1) / BNODES;   // 782 buckets == gemm blocks

    // workspace layout
    size_t o_gcur  = 0;
    size_t o_dinv  = o_gcur  + align256(((size_t)NB + 1) * 4);
    size_t o_WT    = o_dinv  + align256((size_t)N * 4);
    size_t o_hs    = o_WT    + align256((size_t)CH * CH * 2);
    size_t o_pairs = o_hs    + align256((size_t)N * CH * 2);
    size_t o_spill = o_pairs + align256((size_t)NB * CAP * 4);

    int*            gcur  = (int*)((char*)d_ws + o_gcur);
    float*          dinv  = (float*)((char*)d_ws + o_dinv);
    unsigned short* WT    = (unsigned short*)((char*)d_ws + o_WT);
    unsigned short* hs_b  = (unsigned short*)((char*)d_ws + o_hs);
    unsigned int*   pairs = (unsigned int*)((char*)d_ws + o_pairs);
    unsigned int*   spill = (unsigned int*)((char*)d_ws + o_spill);

    const int gCH = (E + 4095) / 4096;          // 4096-edge chunks (196)

    hipMemsetAsync(gcur, 0, ((size_t)NB + 1) * 4, stream);
    k_bin<<<gCH, 256, 0, stream>>>(ei, gcur, pairs, spill, E, NB, W, WT);
    k_gemm<<<NB, 256, 0, stream>>>(x, WT, pairs, gcur, spill, dinv, hs_b, N, NB);
    k_gagg<<<NB, 512, 0, stream>>>((const u16x8*)hs_b, pairs, gcur, spill, dinv, b, out, N, NB);
}

// Round 10
// 75.391 us; speedup vs baseline: 1.2007x; 1.2007x over previous
//
#include <hip/hip_runtime.h>

#define CH 128          // IN_CH == OUT_CH == 128
#define GM 64           // rows per GEMM block == BNODES (gemm block b == bucket b)
#define LDK 136         // padded K stride in LDS
#define BSH 6           // log2(nodes per bucket)
#define BNODES 64       // nodes per bucket
#define CAP 3072        // per-bucket pair capacity (lambda=1024; spill handles excess)
#define MAXB 1024       // LDS cap for bucket arrays (NB=782 for N=50000)
#define EPB 8192        // edges per k_bin block

typedef _Float16 f16x4 __attribute__((ext_vector_type(4)));
typedef float    f32x4 __attribute__((ext_vector_type(4)));
typedef unsigned short u16x8 __attribute__((ext_vector_type(8)));

static __host__ __device__ inline size_t align256(size_t x) { return (x + 255) & ~(size_t)255; }

__device__ inline unsigned short f2b(float f) {   // fp32 -> bf16 RNE
    unsigned int u = __float_as_uint(f);
    return (unsigned short)((u + 0x7fffu + ((u >> 16) & 1u)) >> 16);
}
__device__ inline float b2f(unsigned short h) {
    return __uint_as_float(((unsigned int)h) << 16);
}

// ---------------- bin edges into fixed-capacity buckets + W f16-transpose --------
// pairs[b*CAP + slot] = (src<<6)|(dst&63).  Overflow -> spill list (normally empty).

__global__ __launch_bounds__(256) void k_bin(const int* __restrict__ ei,
                                             int* __restrict__ gcur,      // [nb+1]; [nb]=spill cnt
                                             unsigned int* __restrict__ pairs,
                                             unsigned int* __restrict__ spill,
                                             int e, int nb,
                                             const float* __restrict__ W,
                                             unsigned short* __restrict__ WT) {
    __shared__ int lcnt[MAXB], lbase[MAXB], lpos[MAXB];
    const int t = threadIdx.x;

    // fused W prep: fp32 [k][n] -> f16 bits transposed [n][k]; first 8 blocks
    if (blockIdx.x < 8) {
        int wb = blockIdx.x * 2048;
#pragma unroll
        for (int i = 0; i < 8; ++i) {
            int idx = wb + t + i * 256;
            int k = idx >> 7, nn = idx & 127;
            _Float16 h = (_Float16)W[idx];
            WT[nn * CH + k] = *(unsigned short*)&h;
        }
    }

    for (int i = t; i < nb; i += 256) { lcnt[i] = 0; lpos[i] = 0; }
    __syncthreads();

    // stage 32 edges/thread via int4
    const int base = blockIdx.x * EPB;
    const int e4 = e >> 2;                       // e % 4 == 0 for this problem
    int4 s4[8], d4[8];
#pragma unroll
    for (int r = 0; r < 8; ++r) {
        int q = (base >> 2) + t + r * 256;
        if (q < e4) {
            s4[r] = ((const int4*)ei)[q];
            d4[r] = ((const int4*)(ei + e))[q];
        } else {
            s4[r] = make_int4(-1, -1, -1, -1);
            d4[r] = make_int4(0, 0, 0, 0);
        }
    }
    const int* ss = (const int*)s4;
    const int* dd = (const int*)d4;
#pragma unroll
    for (int i = 0; i < 32; ++i)
        if (ss[i] >= 0) atomicAdd(&lcnt[dd[i] >> BSH], 1);
    __syncthreads();
    for (int i = t; i < nb; i += 256)
        if (lcnt[i]) lbase[i] = atomicAdd(&gcur[i], lcnt[i]);
    __syncthreads();
#pragma unroll
    for (int i = 0; i < 32; ++i) {
        if (ss[i] >= 0) {
            int b = dd[i] >> BSH;
            int p = lbase[b] + atomicAdd(&lpos[b], 1);
            if (p < CAP) {
                pairs[(size_t)b * CAP + p] = ((unsigned)ss[i] << BSH) | (unsigned)(dd[i] & (BNODES - 1));
            } else {
                int sp = atomicAdd(&gcur[nb], 1);
                spill[sp] = ((unsigned)ss[i] << 16) | (unsigned)dd[i];
            }
        }
    }
}

// ---------------- GEMM + fused per-bucket degree/dinv ---------------------------

__global__ __launch_bounds__(256) void k_gemm(const float* __restrict__ x,
                                              const unsigned short* __restrict__ WT,
                                              const unsigned int* __restrict__ pairs,
                                              const int* __restrict__ gcur,
                                              const unsigned int* __restrict__ spill,
                                              float* __restrict__ dinv,
                                              unsigned short* __restrict__ hs_b,
                                              int n, int nb) {
    __shared__ unsigned short sA[GM * LDK];
    __shared__ unsigned short sB[CH * LDK];
    __shared__ int   scnt[GM];
    __shared__ float sdv[GM];

    const int tid = threadIdx.x;
    const int b   = blockIdx.x;
    const int r0  = b * GM;

    if (tid < GM) scnt[tid] = 0;

    const u16x8* Wv = (const u16x8*)WT;
#pragma unroll
    for (int i = 0; i < 8; ++i) {
        int c = tid + i * 256;
        int nr = c >> 4, kq = c & 15;
        *(u16x8*)&sB[nr * LDK + kq * 8] = Wv[c];
    }
#pragma unroll
    for (int i = 0; i < 8; ++i) {
        int c = tid + i * 256;
        int r = c >> 5, cq = c & 31;
        float4 v = make_float4(0.f, 0.f, 0.f, 0.f);
        if (r0 + r < n) v = ((const float4*)x)[(size_t)(r0 + r) * 32 + cq];
        f16x4 h;
        h[0] = (_Float16)v.x; h[1] = (_Float16)v.y;
        h[2] = (_Float16)v.z; h[3] = (_Float16)v.w;
        *(f16x4*)&sA[r * LDK + cq * 4] = h;
    }
    __syncthreads();

    // fused degree histogram (overlaps with MFMA issue below)
    {
        const int cntb = min(gcur[b], CAP);
        const unsigned int* pp = pairs + (size_t)b * CAP;
        for (int j = tid; j < cntb; j += 256)
            atomicAdd(&scnt[pp[j] & (BNODES - 1)], 1);
        const int ns = gcur[nb];
        if (ns > 0) {
            for (int j = tid; j < ns; j += 256) {
                unsigned u = spill[j];
                unsigned du = u & 0xffffu;
                if ((int)(du >> BSH) == b) atomicAdd(&scnt[du & (BNODES - 1)], 1);
            }
        }
    }

    const int lane = tid & 63, w = tid >> 6;
    const int mh = (w >> 1) * 32;
    const int nh = (w & 1) * 64;
    const int fr = lane & 15, fg = lane >> 4;

    f32x4 acc[2][4];
#pragma unroll
    for (int a = 0; a < 2; ++a)
#pragma unroll
        for (int bq = 0; bq < 4; ++bq) acc[a][bq] = (f32x4){0.f, 0.f, 0.f, 0.f};

#pragma unroll
    for (int ks = 0; ks < 8; ++ks) {
        const int kk = ks * 16 + fg * 4;
        f16x4 a0 = *(const f16x4*)&sA[(mh + fr) * LDK + kk];
        f16x4 a1 = *(const f16x4*)&sA[(mh + 16 + fr) * LDK + kk];
        f16x4 b0 = *(const f16x4*)&sB[(nh + fr) * LDK + kk];
        f16x4 b1 = *(const f16x4*)&sB[(nh + 16 + fr) * LDK + kk];
        f16x4 b2 = *(const f16x4*)&sB[(nh + 32 + fr) * LDK + kk];
        f16x4 b3 = *(const f16x4*)&sB[(nh + 48 + fr) * LDK + kk];
        acc[0][0] = __builtin_amdgcn_mfma_f32_16x16x16f16(a0, b0, acc[0][0], 0, 0, 0);
        acc[0][1] = __builtin_amdgcn_mfma_f32_16x16x16f16(a0, b1, acc[0][1], 0, 0, 0);
        acc[0][2] = __builtin_amdgcn_mfma_f32_16x16x16f16(a0, b2, acc[0][2], 0, 0, 0);
        acc[0][3] = __builtin_amdgcn_mfma_f32_16x16x16f16(a0, b3, acc[0][3], 0, 0, 0);
        acc[1][0] = __builtin_amdgcn_mfma_f32_16x16x16f16(a1, b0, acc[1][0], 0, 0, 0);
        acc[1][1] = __builtin_amdgcn_mfma_f32_16x16x16f16(a1, b1, acc[1][1], 0, 0, 0);
        acc[1][2] = __builtin_amdgcn_mfma_f32_16x16x16f16(a1, b2, acc[1][2], 0, 0, 0);
        acc[1][3] = __builtin_amdgcn_mfma_f32_16x16x16f16(a1, b3, acc[1][3], 0, 0, 0);
    }
    __syncthreads();                 // histogram atomics complete

    if (tid < GM) {
        float dv = rsqrtf((float)scnt[tid] + 1.0f);
        sdv[tid] = dv;
        int node = r0 + tid;
        if (node < n) dinv[node] = dv;
    }
    __syncthreads();                 // sdv visible to all

#pragma unroll
    for (int mt = 0; mt < 2; ++mt) {
        int lbase_r = mh + mt * 16 + fg * 4;
        int rbase = r0 + lbase_r;
#pragma unroll
        for (int nt = 0; nt < 4; ++nt) {
            int col = nh + nt * 16 + fr;
#pragma unroll
            for (int rg = 0; rg < 4; ++rg) {
                if (rbase + rg < n)
                    hs_b[(size_t)(rbase + rg) * CH + col] = f2b(acc[mt][nt][rg] * sdv[lbase_r + rg]);
            }
        }
    }
}

// ---------------- fused sort+gather per bucket --------------------------------

__global__ __launch_bounds__(256) void k_gagg(const u16x8* __restrict__ h8,
                                              const unsigned int* __restrict__ pairs,
                                              const int* __restrict__ gcur,
                                              const unsigned int* __restrict__ spill,
                                              const float* __restrict__ dinv,
                                              const float* __restrict__ bias,
                                              float* __restrict__ out, int n, int nb) {
    __shared__ unsigned int   sPairs[CAP];
    __shared__ unsigned short sSort[CAP];
    __shared__ int scnt[BNODES], sexcl[BNODES], scur[BNODES];
    __shared__ float sdinv[BNODES];

    const int t = threadIdx.x, b = blockIdx.x;
    const int n0 = b * BNODES;

    if (t < BNODES) {
        scnt[t] = 0;
        int node = n0 + t;
        sdinv[t] = (node < n) ? dinv[node] : 0.f;
    }
    __syncthreads();

    const int cntb = min(gcur[b], CAP);
    const unsigned int* pp = pairs + (size_t)b * CAP;
    for (int j = t; j < cntb; j += 256) {
        unsigned p = pp[j];
        sPairs[j] = p;
        atomicAdd(&scnt[p & (BNODES - 1)], 1);
    }
    __syncthreads();

    if (t < 64) {          // BNODES == 64: one wave scans the counts
        int c = scnt[t];
        int s = c;
#pragma unroll
        for (int off = 1; off < 64; off <<= 1) {
            int tv = __shfl_up(s, off, 64);
            if (t >= off) s += tv;
        }
        sexcl[t] = s - c;
        scur[t]  = s - c;
    }
    __syncthreads();

    for (int j = t; j < cntb; j += 256) {
        unsigned p = sPairs[j];
        int pos = atomicAdd(&scur[p & (BNODES - 1)], 1);
        sSort[pos] = (unsigned short)(p >> BSH);
    }
    __syncthreads();

    const int g = t >> 4, lane = t & 15;        // 16 groups of 16 lanes
    const int ns = gcur[nb];
#pragma unroll
    for (int k = 0; k < BNODES / 16; ++k) {     // 4 nodes per group
        const int nl = g * (BNODES / 16) + k;
        const int node = n0 + nl;
        if (node >= n) break;

        float acc[8];
        {
            u16x8 v = h8[(size_t)node * 16 + lane];   // self term
#pragma unroll
            for (int i = 0; i < 8; ++i) acc[i] = b2f(v[i]);
        }

        int j = sexcl[nl];
        const int end = j + scnt[nl];
        for (; j + 4 <= end; j += 4) {
            int s0 = sSort[j + 0], s1 = sSort[j + 1];
            int s2 = sSort[j + 2], s3 = sSort[j + 3];
            u16x8 v0 = h8[(size_t)s0 * 16 + lane];
            u16x8 v1 = h8[(size_t)s1 * 16 + lane];
            u16x8 v2 = h8[(size_t)s2 * 16 + lane];
            u16x8 v3 = h8[(size_t)s3 * 16 + lane];
#pragma unroll
            for (int i = 0; i < 8; ++i)
                acc[i] += (b2f(v0[i]) + b2f(v1[i])) + (b2f(v2[i]) + b2f(v3[i]));
        }
        for (; j < end; ++j) {
            u16x8 v = h8[(size_t)sSort[j] * 16 + lane];
#pragma unroll
            for (int i = 0; i < 8; ++i) acc[i] += b2f(v[i]);
        }

        if (ns > 0) {      // cold path: spilled edges for this node
            for (int q = 0; q < ns; ++q) {
                unsigned u = spill[q];
                if ((int)(u & 0xffffu) == node) {
                    u16x8 v = h8[(size_t)(u >> 16) * 16 + lane];
#pragma unroll
                    for (int i = 0; i < 8; ++i) acc[i] += b2f(v[i]);
                }
            }
        }

        const float di = sdinv[nl];
        const float* bp = bias + lane * 8;
        float4 o0, o1;
        o0.x = fmaxf(fmaf(acc[0], di, bp[0]), 0.f);
        o0.y = fmaxf(fmaf(acc[1], di, bp[1]), 0.f);
        o0.z = fmaxf(fmaf(acc[2], di, bp[2]), 0.f);
        o0.w = fmaxf(fmaf(acc[3], di, bp[3]), 0.f);
        o1.x = fmaxf(fmaf(acc[4], di, bp[4]), 0.f);
        o1.y = fmaxf(fmaf(acc[5], di, bp[5]), 0.f);
        o1.z = fmaxf(fmaf(acc[6], di, bp[6]), 0.f);
        o1.w = fmaxf(fmaf(acc[7], di, bp[7]), 0.f);
        float4* op = (float4*)(out + (size_t)node * CH + lane * 8);
        op[0] = o0;
        op[1] = o1;
    }
}

// ---------------- launch ----------------

extern "C" void kernel_launch(void* const* d_in, const int* in_sizes, int n_in,
                              void* d_out, int out_size, void* d_ws, size_t ws_size,
                              hipStream_t stream) {
    const float* x  = (const float*)d_in[0];
    const int*   ei = (const int*)d_in[1];
    const float* W  = (const float*)d_in[2];
    const float* b  = (const float*)d_in[3];
    float* out = (float*)d_out;

    const int N = in_sizes[0] / CH;     // 50000 (node ids < 65536 -> 16-bit packing valid)
    const int E = in_sizes[1] / 2;      // 800000

    const int NB = (N + BNODES - 1) / BNODES;   // 782 buckets == gemm blocks

    // workspace layout
    size_t o_gcur  = 0;
    size_t o_dinv  = o_gcur  + align256(((size_t)NB + 1) * 4);
    size_t o_WT    = o_dinv  + align256((size_t)N * 4);
    size_t o_hs    = o_WT    + align256((size_t)CH * CH * 2);
    size_t o_pairs = o_hs    + align256((size_t)N * CH * 2);
    size_t o_spill = o_pairs + align256((size_t)NB * CAP * 4);

    int*            gcur  = (int*)((char*)d_ws + o_gcur);
    float*          dinv  = (float*)((char*)d_ws + o_dinv);
    unsigned short* WT    = (unsigned short*)((char*)d_ws + o_WT);
    unsigned short* hs_b  = (unsigned short*)((char*)d_ws + o_hs);
    unsigned int*   pairs = (unsigned int*)((char*)d_ws + o_pairs);
    unsigned int*   spill = (unsigned int*)((char*)d_ws + o_spill);

    const int gCH = (E + EPB - 1) / EPB;        // 8192-edge chunks (98)

    hipMemsetAsync(gcur, 0, ((size_t)NB + 1) * 4, stream);
    k_bin<<<gCH, 256, 0, stream>>>(ei, gcur, pairs, spill, E, NB, W, WT);
    k_gemm<<<NB, 256, 0, stream>>>(x, WT, pairs, gcur, spill, dinv, hs_b, N, NB);
    k_gagg<<<NB, 256, 0, stream>>>((const u16x8*)hs_b, pairs, gcur, spill, dinv, b, out, N, NB);
}

// Round 11
// 74.270 us; speedup vs baseline: 1.2188x; 1.0151x over previous
//
#include <hip/hip_runtime.h>

#define CH 128          // IN_CH == OUT_CH == 128
#define GM 64           // rows per GEMM block == 2 buckets
#define LDK 136         // padded K stride in LDS
#define BSH 5           // log2(nodes per bucket)
#define BNODES 32       // nodes per bucket
#define CAP 768         // per-bucket pair capacity (lambda=512; spill handles excess)
#define MAXB 2048       // LDS cap for bucket arrays (NB=1563 for N=50000)
#define EPB 8192        // edges per k_bin block

typedef _Float16 f16x4 __attribute__((ext_vector_type(4)));
typedef float    f32x4 __attribute__((ext_vector_type(4)));
typedef unsigned short u16x8 __attribute__((ext_vector_type(8)));

static __host__ __device__ inline size_t align256(size_t x) { return (x + 255) & ~(size_t)255; }

__device__ inline unsigned short f2b(float f) {   // fp32 -> bf16 RNE
    unsigned int u = __float_as_uint(f);
    return (unsigned short)((u + 0x7fffu + ((u >> 16) & 1u)) >> 16);
}
__device__ inline float b2f(unsigned short h) {
    return __uint_as_float(((unsigned int)h) << 16);
}

// ---------------- bin edges into fixed-capacity buckets + W f16-transpose --------
// pairs[b*CAP + slot] = (src<<5)|(dst&31).  Overflow -> spill list (normally empty).

__global__ __launch_bounds__(256) void k_bin(const int* __restrict__ ei,
                                             int* __restrict__ gcur,      // [nb+1]; [nb]=spill cnt
                                             unsigned int* __restrict__ pairs,
                                             unsigned int* __restrict__ spill,
                                             int e, int nb,
                                             const float* __restrict__ W,
                                             unsigned short* __restrict__ WT) {
    __shared__ int lcnt[MAXB], lbase[MAXB], lpos[MAXB];
    const int t = threadIdx.x;

    // fused W prep: fp32 [k][n] -> f16 bits transposed [n][k]; first 8 blocks
    if (blockIdx.x < 8) {
        int wb = blockIdx.x * 2048;
#pragma unroll
        for (int i = 0; i < 8; ++i) {
            int idx = wb + t + i * 256;
            int k = idx >> 7, nn = idx & 127;
            _Float16 h = (_Float16)W[idx];
            WT[nn * CH + k] = *(unsigned short*)&h;
        }
    }

    for (int i = t; i < nb; i += 256) { lcnt[i] = 0; lpos[i] = 0; }
    __syncthreads();

    // stage 32 edges/thread via int4
    const int base = blockIdx.x * EPB;
    const int e4 = e >> 2;                       // e % 4 == 0 for this problem
    int4 s4[8], d4[8];
#pragma unroll
    for (int r = 0; r < 8; ++r) {
        int q = (base >> 2) + t + r * 256;
        if (q < e4) {
            s4[r] = ((const int4*)ei)[q];
            d4[r] = ((const int4*)(ei + e))[q];
        } else {
            s4[r] = make_int4(-1, -1, -1, -1);
            d4[r] = make_int4(0, 0, 0, 0);
        }
    }
    const int* ss = (const int*)s4;
    const int* dd = (const int*)d4;
#pragma unroll
    for (int i = 0; i < 32; ++i)
        if (ss[i] >= 0) atomicAdd(&lcnt[dd[i] >> BSH], 1);
    __syncthreads();
    for (int i = t; i < nb; i += 256)
        if (lcnt[i]) lbase[i] = atomicAdd(&gcur[i], lcnt[i]);
    __syncthreads();
#pragma unroll
    for (int i = 0; i < 32; ++i) {
        if (ss[i] >= 0) {
            int b = dd[i] >> BSH;
            int p = lbase[b] + atomicAdd(&lpos[b], 1);
            if (p < CAP) {
                pairs[(size_t)b * CAP + p] = ((unsigned)ss[i] << BSH) | (unsigned)(dd[i] & (BNODES - 1));
            } else {
                int sp = atomicAdd(&gcur[nb], 1);
                spill[sp] = ((unsigned)ss[i] << 16) | (unsigned)dd[i];
            }
        }
    }
}

// ---------------- GEMM + fused degree/dinv (block b == buckets 2b, 2b+1) --------

__global__ __launch_bounds__(256) void k_gemm(const float* __restrict__ x,
                                              const unsigned short* __restrict__ WT,
                                              const unsigned int* __restrict__ pairs,
                                              const int* __restrict__ gcur,
                                              const unsigned int* __restrict__ spill,
                                              float* __restrict__ dinv,
                                              unsigned short* __restrict__ hs_b,
                                              int n, int nb) {
    __shared__ unsigned short sA[GM * LDK];
    __shared__ unsigned short sB[CH * LDK];
    __shared__ int   scnt[GM];
    __shared__ float sdv[GM];

    const int tid = threadIdx.x;
    const int b   = blockIdx.x;
    const int r0  = b * GM;

    if (tid < GM) scnt[tid] = 0;

    const u16x8* Wv = (const u16x8*)WT;
#pragma unroll
    for (int i = 0; i < 8; ++i) {
        int c = tid + i * 256;
        int nr = c >> 4, kq = c & 15;
        *(u16x8*)&sB[nr * LDK + kq * 8] = Wv[c];
    }
#pragma unroll
    for (int i = 0; i < 8; ++i) {
        int c = tid + i * 256;
        int r = c >> 5, cq = c & 31;
        float4 v = make_float4(0.f, 0.f, 0.f, 0.f);
        if (r0 + r < n) v = ((const float4*)x)[(size_t)(r0 + r) * 32 + cq];
        f16x4 h;
        h[0] = (_Float16)v.x; h[1] = (_Float16)v.y;
        h[2] = (_Float16)v.z; h[3] = (_Float16)v.w;
        *(f16x4*)&sA[r * LDK + cq * 4] = h;
    }
    __syncthreads();

    // fused degree histogram over both buckets (overlaps with MFMA issue below)
    {
#pragma unroll
        for (int q = 0; q < 2; ++q) {
            const int bk = 2 * b + q;
            if (bk < nb) {
                const int cntb = min(gcur[bk], CAP);
                const unsigned int* pp = pairs + (size_t)bk * CAP;
                for (int j = tid; j < cntb; j += 256)
                    atomicAdd(&scnt[q * BNODES + (pp[j] & (BNODES - 1))], 1);
            }
        }
        const int ns = gcur[nb];
        if (ns > 0) {
            for (int j = tid; j < ns; j += 256) {
                unsigned u = spill[j];
                unsigned du = u & 0xffffu;
                if ((int)(du >> 6) == b) atomicAdd(&scnt[du & 63], 1);
            }
        }
    }

    const int lane = tid & 63, w = tid >> 6;
    const int mh = (w >> 1) * 32;
    const int nh = (w & 1) * 64;
    const int fr = lane & 15, fg = lane >> 4;

    f32x4 acc[2][4];
#pragma unroll
    for (int a = 0; a < 2; ++a)
#pragma unroll
        for (int bq = 0; bq < 4; ++bq) acc[a][bq] = (f32x4){0.f, 0.f, 0.f, 0.f};

#pragma unroll
    for (int ks = 0; ks < 8; ++ks) {
        const int kk = ks * 16 + fg * 4;
        f16x4 a0 = *(const f16x4*)&sA[(mh + fr) * LDK + kk];
        f16x4 a1 = *(const f16x4*)&sA[(mh + 16 + fr) * LDK + kk];
        f16x4 b0 = *(const f16x4*)&sB[(nh + fr) * LDK + kk];
        f16x4 b1 = *(const f16x4*)&sB[(nh + 16 + fr) * LDK + kk];
        f16x4 b2 = *(const f16x4*)&sB[(nh + 32 + fr) * LDK + kk];
        f16x4 b3 = *(const f16x4*)&sB[(nh + 48 + fr) * LDK + kk];
        acc[0][0] = __builtin_amdgcn_mfma_f32_16x16x16f16(a0, b0, acc[0][0], 0, 0, 0);
        acc[0][1] = __builtin_amdgcn_mfma_f32_16x16x16f16(a0, b1, acc[0][1], 0, 0, 0);
        acc[0][2] = __builtin_amdgcn_mfma_f32_16x16x16f16(a0, b2, acc[0][2], 0, 0, 0);
        acc[0][3] = __builtin_amdgcn_mfma_f32_16x16x16f16(a0, b3, acc[0][3], 0, 0, 0);
        acc[1][0] = __builtin_amdgcn_mfma_f32_16x16x16f16(a1, b0, acc[1][0], 0, 0, 0);
        acc[1][1] = __builtin_amdgcn_mfma_f32_16x16x16f16(a1, b1, acc[1][1], 0, 0, 0);
        acc[1][2] = __builtin_amdgcn_mfma_f32_16x16x16f16(a1, b2, acc[1][2], 0, 0, 0);
        acc[1][3] = __builtin_amdgcn_mfma_f32_16x16x16f16(a1, b3, acc[1][3], 0, 0, 0);
    }
    __syncthreads();                 // histogram atomics complete

    if (tid < GM) {
        float dv = rsqrtf((float)scnt[tid] + 1.0f);
        sdv[tid] = dv;
        int node = r0 + tid;
        if (node < n) dinv[node] = dv;
    }
    __syncthreads();                 // sdv visible to all

#pragma unroll
    for (int mt = 0; mt < 2; ++mt) {
        int lbase_r = mh + mt * 16 + fg * 4;
        int rbase = r0 + lbase_r;
#pragma unroll
        for (int nt = 0; nt < 4; ++nt) {
            int col = nh + nt * 16 + fr;
#pragma unroll
            for (int rg = 0; rg < 4; ++rg) {
                if (rbase + rg < n)
                    hs_b[(size_t)(rbase + rg) * CH + col] = f2b(acc[mt][nt][rg] * sdv[lbase_r + rg]);
            }
        }
    }
}

// ---------------- fused sort+gather per bucket (32 nodes, 256 threads) ---------

__global__ __launch_bounds__(256) void k_gagg(const u16x8* __restrict__ h8,
                                              const unsigned int* __restrict__ pairs,
                                              const int* __restrict__ gcur,
                                              const unsigned int* __restrict__ spill,
                                              const float* __restrict__ dinv,
                                              const float* __restrict__ bias,
                                              float* __restrict__ out, int n, int nb) {
    __shared__ unsigned int   sPairs[CAP];
    __shared__ unsigned short sSort[CAP];
    __shared__ int scnt[BNODES], sexcl[BNODES], scur[BNODES];
    __shared__ float sdinv[BNODES];

    const int t = threadIdx.x, b = blockIdx.x;
    const int n0 = b * BNODES;

    if (t < BNODES) {
        scnt[t] = 0;
        int node = n0 + t;
        sdinv[t] = (node < n) ? dinv[node] : 0.f;
    }
    __syncthreads();

    const int cntb = min(gcur[b], CAP);
    const unsigned int* pp = pairs + (size_t)b * CAP;
    for (int j = t; j < cntb; j += 256) {
        unsigned p = pp[j];
        sPairs[j] = p;
        atomicAdd(&scnt[p & (BNODES - 1)], 1);
    }
    __syncthreads();

    if (t < 32) {          // BNODES == 32: lanes 0..31 of wave 0 scan the counts
        int c = scnt[t];
        int s = c;
#pragma unroll
        for (int off = 1; off < 32; off <<= 1) {
            int tv = __shfl_up(s, off, 64);
            if (t >= off) s += tv;
        }
        sexcl[t] = s - c;
        scur[t]  = s - c;
    }
    __syncthreads();

    for (int j = t; j < cntb; j += 256) {
        unsigned p = sPairs[j];
        int pos = atomicAdd(&scur[p & (BNODES - 1)], 1);
        sSort[pos] = (unsigned short)(p >> BSH);
    }
    __syncthreads();

    const int g = t >> 4, lane = t & 15;        // 16 groups of 16 lanes
    const int ns = gcur[nb];
#pragma unroll
    for (int k = 0; k < BNODES / 16; ++k) {     // 2 nodes per group
        const int nl = g * (BNODES / 16) + k;
        const int node = n0 + nl;
        if (node >= n) break;

        float acc[8];
        {
            u16x8 v = h8[(size_t)node * 16 + lane];   // self term
#pragma unroll
            for (int i = 0; i < 8; ++i) acc[i] = b2f(v[i]);
        }

        int j = sexcl[nl];
        const int end = j + scnt[nl];
        for (; j + 4 <= end; j += 4) {
            int s0 = sSort[j + 0], s1 = sSort[j + 1];
            int s2 = sSort[j + 2], s3 = sSort[j + 3];
            u16x8 v0 = h8[(size_t)s0 * 16 + lane];
            u16x8 v1 = h8[(size_t)s1 * 16 + lane];
            u16x8 v2 = h8[(size_t)s2 * 16 + lane];
            u16x8 v3 = h8[(size_t)s3 * 16 + lane];
#pragma unroll
            for (int i = 0; i < 8; ++i)
                acc[i] += (b2f(v0[i]) + b2f(v1[i])) + (b2f(v2[i]) + b2f(v3[i]));
        }
        for (; j < end; ++j) {
            u16x8 v = h8[(size_t)sSort[j] * 16 + lane];
#pragma unroll
            for (int i = 0; i < 8; ++i) acc[i] += b2f(v[i]);
        }

        if (ns > 0) {      // cold path: spilled edges for this node
            for (int q = 0; q < ns; ++q) {
                unsigned u = spill[q];
                if ((int)(u & 0xffffu) == node) {
                    u16x8 v = h8[(size_t)(u >> 16) * 16 + lane];
#pragma unroll
                    for (int i = 0; i < 8; ++i) acc[i] += b2f(v[i]);
                }
            }
        }

        const float di = sdinv[nl];
        const float* bp = bias + lane * 8;
        float4 o0, o1;
        o0.x = fmaxf(fmaf(acc[0], di, bp[0]), 0.f);
        o0.y = fmaxf(fmaf(acc[1], di, bp[1]), 0.f);
        o0.z = fmaxf(fmaf(acc[2], di, bp[2]), 0.f);
        o0.w = fmaxf(fmaf(acc[3], di, bp[3]), 0.f);
        o1.x = fmaxf(fmaf(acc[4], di, bp[4]), 0.f);
        o1.y = fmaxf(fmaf(acc[5], di, bp[5]), 0.f);
        o1.z = fmaxf(fmaf(acc[6], di, bp[6]), 0.f);
        o1.w = fmaxf(fmaf(acc[7], di, bp[7]), 0.f);
        float4* op = (float4*)(out + (size_t)node * CH + lane * 8);
        op[0] = o0;
        op[1] = o1;
    }
}

// ---------------- launch ----------------

extern "C" void kernel_launch(void* const* d_in, const int* in_sizes, int n_in,
                              void* d_out, int out_size, void* d_ws, size_t ws_size,
                              hipStream_t stream) {
    const float* x  = (const float*)d_in[0];
    const int*   ei = (const int*)d_in[1];
    const float* W  = (const float*)d_in[2];
    const float* b  = (const float*)d_in[3];
    float* out = (float*)d_out;

    const int N = in_sizes[0] / CH;     // 50000 (node ids < 65536 -> 16-bit packing valid)
    const int E = in_sizes[1] / 2;      // 800000

    const int NB = (N + BNODES - 1) / BNODES;   // 1563 buckets
    const int GB = (N + GM - 1) / GM;           // 782 gemm blocks

    // workspace layout
    size_t o_gcur  = 0;
    size_t o_dinv  = o_gcur  + align256(((size_t)NB + 1) * 4);
    size_t o_WT    = o_dinv  + align256((size_t)N * 4);
    size_t o_hs    = o_WT    + align256((size_t)CH * CH * 2);
    size_t o_pairs = o_hs    + align256((size_t)N * CH * 2);
    size_t o_spill = o_pairs + align256((size_t)NB * CAP * 4);

    int*            gcur  = (int*)((char*)d_ws + o_gcur);
    float*          dinv  = (float*)((char*)d_ws + o_dinv);
    unsigned short* WT    = (unsigned short*)((char*)d_ws + o_WT);
    unsigned short* hs_b  = (unsigned short*)((char*)d_ws + o_hs);
    unsigned int*   pairs = (unsigned int*)((char*)d_ws + o_pairs);
    unsigned int*   spill = (unsigned int*)((char*)d_ws + o_spill);

    const int gCH = (E + EPB - 1) / EPB;        // 8192-edge chunks (98)

    hipMemsetAsync(gcur, 0, ((size_t)NB + 1) * 4, stream);
    k_bin<<<gCH, 256, 0, stream>>>(ei, gcur, pairs, spill, E, NB, W, WT);
    k_gemm<<<GB, 256, 0, stream>>>(x, WT, pairs, gcur, spill, dinv, hs_b, N, NB);
    k_gagg<<<NB, 256, 0, stream>>>((const u16x8*)hs_b, pairs, gcur, spill, dinv, b, out, N, NB);
}